// Round 7
// baseline (406.654 us; speedup 1.0000x reference)
//
#include <hip/hip_runtime.h>
#include <math.h>

#define B_ 4
#define C_ 512
#define N_ 4096
#define LOG2E 1.44269504088896f

typedef __attribute__((ext_vector_type(8))) short s8v;   // 8 bf16
typedef __attribute__((ext_vector_type(4))) float f4v;   // MFMA acc

#define MF32(a, b, c) __builtin_amdgcn_mfma_f32_16x16x32_bf16(a, b, c, 0, 0, 0)

static __device__ __forceinline__ ushort f2bf(float f) {   // RNE
    unsigned u = __float_as_uint(f);
    u += 0x7FFFu + ((u >> 16) & 1u);
    return (ushort)(u >> 16);
}
static __device__ __forceinline__ unsigned pack2bf(float a, float b) {
    unsigned ua = __float_as_uint(a); ua += 0x7FFFu + ((ua >> 16) & 1u);
    unsigned ub = __float_as_uint(b); ub += 0x7FFFu + ((ub >> 16) & 1u);
    return (ua >> 16) | (ub & 0xffff0000u);
}

// ---------------------------------------------------------------------------
// Pass A: Wq|Wk|Wv -> Wb [640][512] bf16
// ---------------------------------------------------------------------------
__global__ __launch_bounds__(256) void wconv_kernel(
    const float* __restrict__ Wq, const float* __restrict__ Wk,
    const float* __restrict__ Wv, ushort* __restrict__ Wb)
{
    const int row = blockIdx.x;
    const float* src = row < 64 ? Wq + (size_t)row * C_
                     : row < 128 ? Wk + (size_t)(row - 64) * C_
                     : Wv + (size_t)(row - 128) * C_;
    const int t2 = threadIdx.x * 2;
    float2 v = *(const float2*)&src[t2];
    ushort2 o; o.x = f2bf(v.x); o.y = f2bf(v.y);
    *(ushort2*)&Wb[(size_t)row * C_ + t2] = o;
}

// ---------------------------------------------------------------------------
// Pass B: fused QKV. grid (128 n-tiles, B), block 256 (4 waves, 3 blocks/CU).
// LDS: Xs [32 n][552 c] bf16 (stride 552: 16B-aligned rows, 276 dw = 4 mod 8
// -> staging writes ~4-way instead of 16-way, frag reads ~2-way free).
// Wave w: o-rows w*160..+159 (10 tiles of 16) x 32 n. Rows <64 q (x log2e),
// <128 k (stored transposed [b][n][64]); rows >=128: v with swapped MFMA
// operands (D[m=n][col=o]) -> ushort4 stores along n into vB [b][c][n].
// ---------------------------------------------------------------------------
__global__ __launch_bounds__(256, 3) void qkv_fused(
    const float* __restrict__ x, const ushort* __restrict__ Wb,
    const float* __restrict__ bq, const float* __restrict__ bk,
    const float* __restrict__ bv,
    ushort* __restrict__ qT, ushort* __restrict__ kT, ushort* __restrict__ vB)
{
    __shared__ ushort Xs[32 * 552];

    const int tid = threadIdx.x, w = tid >> 6, lane = tid & 63;
    const int li = lane & 15, qd = lane >> 4;
    const int n0 = blockIdx.x * 32, b = blockIdx.y;

    // ---- stage x[c][n0..n0+31] -> Xs[n][c] bf16 ----
    {
        const int cg = tid >> 3;       // 0..31
        const int ch = tid & 7;        // n-chunk of 4
        #pragma unroll
        for (int r = 0; r < 16; ++r) {
            const int c = r * 32 + cg;
            float4 v = *(const float4*)&x[((size_t)b * C_ + c) * N_ + n0 + ch * 4];
            Xs[(ch * 4 + 0) * 552 + c] = f2bf(v.x);
            Xs[(ch * 4 + 1) * 552 + c] = f2bf(v.y);
            Xs[(ch * 4 + 2) * 552 + c] = f2bf(v.z);
            Xs[(ch * 4 + 3) * 552 + c] = f2bf(v.w);
        }
    }
    __syncthreads();

    const int rb0 = w * 160;
    f4v acc[10][2];
    #pragma unroll
    for (int ot = 0; ot < 10; ++ot)
        #pragma unroll
        for (int nt = 0; nt < 2; ++nt)
            acc[ot][nt] = (f4v){0.f, 0.f, 0.f, 0.f};

    #pragma unroll 1
    for (int kc = 0; kc < C_; kc += 32) {
        s8v aw[10], bx[2];
        #pragma unroll
        for (int ot = 0; ot < 10; ++ot)
            aw[ot] = *(const s8v*)&Wb[(size_t)(rb0 + ot * 16 + li) * C_ + kc + qd * 8];
        #pragma unroll
        for (int nt = 0; nt < 2; ++nt)
            bx[nt] = *(const s8v*)&Xs[(nt * 16 + li) * 552 + kc + qd * 8];
        #pragma unroll
        for (int ot = 0; ot < 10; ++ot) {
            if (rb0 + ot * 16 >= 128) {       // v: swapped -> D[m=n][col=o]
                #pragma unroll
                for (int nt = 0; nt < 2; ++nt)
                    acc[ot][nt] = MF32(bx[nt], aw[ot], acc[ot][nt]);
            } else {                           // q/k: D[m=o][col=n]
                #pragma unroll
                for (int nt = 0; nt < 2; ++nt)
                    acc[ot][nt] = MF32(aw[ot], bx[nt], acc[ot][nt]);
            }
        }
    }

    #pragma unroll
    for (int ot = 0; ot < 10; ++ot) {
        const int rb = rb0 + ot * 16;
        if (rb < 128) {   // q or k: lane col = n, rows = o (qd*4+r)
            ushort* dst = rb < 64 ? qT : kT;
            const float* bias = rb < 64 ? bq : bk;
            const int ob = (rb < 64 ? rb : rb - 64) + qd * 4;
            const float sc = rb < 64 ? LOG2E : 1.0f;
            #pragma unroll
            for (int nt = 0; nt < 2; ++nt) {
                const int n = n0 + nt * 16 + li;
                ushort4 o;
                o.x = f2bf((acc[ot][nt][0] + bias[ob + 0]) * sc);
                o.y = f2bf((acc[ot][nt][1] + bias[ob + 1]) * sc);
                o.z = f2bf((acc[ot][nt][2] + bias[ob + 2]) * sc);
                o.w = f2bf((acc[ot][nt][3] + bias[ob + 3]) * sc);
                *(ushort4*)&dst[((size_t)b * N_ + n) * 64 + ob] = o;
            }
        } else {          // v: lane col = o (c), rows = n
            const int c = rb - 128 + li;
            const float bb = bv[c];
            #pragma unroll
            for (int nt = 0; nt < 2; ++nt) {
                const int n = n0 + nt * 16 + qd * 4;
                ushort4 o;
                o.x = f2bf(acc[ot][nt][0] + bb);
                o.y = f2bf(acc[ot][nt][1] + bb);
                o.z = f2bf(acc[ot][nt][2] + bb);
                o.w = f2bf(acc[ot][nt][3] + bb);
                *(ushort4*)&vB[((size_t)b * C_ + c) * N_ + n] = o;
            }
        }
    }
}

// ---------------------------------------------------------------------------
// Pass C: MFMA flash attention. i-tile 32, grid 512 (1-D, 2 blocks/CU).
// XCD swizzle: b = blockIdx.x & 3 -> each XCD sees ONE batch (V L2-resident).
// Wave w: S j-slice w*16 of the 128-j tile AND PV c-slice w*64.
// PV operand-swapped: D[m=i][n=c] -> lane owns 4 consecutive i => float4
// epilogue, no transpose. P ping-pong [32][136] bf16, 1 barrier/iter.
// LDS 18560 B. exp2 (log2e folded into q), per-lane l partials.
// ---------------------------------------------------------------------------
__device__ __forceinline__ void pv_chunk(
    const ushort* __restrict__ Pr, int li, int qd, int chunk,
    const s8v* vf, f4v (&acc)[4][2])
{
    s8v pf[2];
    #pragma unroll
    for (int it = 0; it < 2; ++it)
        pf[it] = *(const s8v*)&Pr[(size_t)(it * 16 + li) * 136 + chunk * 32 + qd * 8];
    #pragma unroll
    for (int ct = 0; ct < 4; ++ct)
        #pragma unroll
        for (int it = 0; it < 2; ++it)
            acc[ct][it] = MF32(pf[it], vf[ct], acc[ct][it]);   // D[m=i][n=c]
}

__global__ __launch_bounds__(512, 4) void attn_mfma(
    const ushort* __restrict__ qT, const ushort* __restrict__ kT,
    const ushort* __restrict__ vB, const float* __restrict__ x,
    const float* __restrict__ gamma, float* __restrict__ out)
{
    extern __shared__ char smem[];
    ushort* Pb0  = (ushort*)smem;               // [32][136] 8704 B
    ushort* Pb1  = (ushort*)(smem + 8704);      // [32][136]
    float*  l_s  = (float*)(smem + 17408);      // [8][32]
    float*  linv = (float*)(smem + 18432);      // [32]

    const int tid = threadIdx.x, w = tid >> 6, lane = tid & 63;
    const int li = lane & 15, qd = lane >> 4;
    const int b      = blockIdx.x & 3;           // XCD-locality swizzle
    const int i_base = (blockIdx.x >> 2) * 32;

    const ushort* qTb = qT + (size_t)b * N_ * 64;
    const ushort* kTb = kT + (size_t)b * N_ * 64;
    const ushort* vBb = vB + (size_t)b * C_ * N_;

    // persistent Q fragments (B-operand: n=i at li, k=c at qd*8)
    s8v qf[2][2];
    #pragma unroll
    for (int it = 0; it < 2; ++it)
        #pragma unroll
        for (int ks = 0; ks < 2; ++ks)
            qf[it][ks] = *(const s8v*)&qTb[(size_t)(i_base + it * 16 + li) * 64 + ks * 32 + qd * 8];

    f4v acc[4][2];   // [ct][it]: i = i_base+it*16+qd*4+r, c = w*64+ct*16+li
    #pragma unroll
    for (int ct = 0; ct < 4; ++ct)
        #pragma unroll
        for (int it = 0; it < 2; ++it)
            acc[ct][it] = (f4v){0.f, 0.f, 0.f, 0.f};
    float lp[2] = {0.f, 0.f};

    const ushort* kptr = kTb + (size_t)(w * 16 + li) * 64 + qd * 8;
    const ushort* vptr[4];
    #pragma unroll
    for (int ct = 0; ct < 4; ++ct)
        vptr[ct] = vBb + (size_t)(w * 64 + ct * 16 + li) * N_ + qd * 8;

    // ---- prologue: S(0) -> Pb0 ----
    {
        s8v kf0 = *(const s8v*)(kptr);
        s8v kf1 = *(const s8v*)(kptr + 32);
        f4v sac[2];
        #pragma unroll
        for (int it = 0; it < 2; ++it) {
            sac[it] = (f4v){0.f, 0.f, 0.f, 0.f};
            sac[it] = MF32(kf0, qf[it][0], sac[it]);
            sac[it] = MF32(kf1, qf[it][1], sac[it]);
        }
        #pragma unroll
        for (int it = 0; it < 2; ++it) {
            const float p0 = exp2f(sac[it][0]);
            const float p1 = exp2f(sac[it][1]);
            const float p2 = exp2f(sac[it][2]);
            const float p3 = exp2f(sac[it][3]);
            lp[it] += (p0 + p1) + (p2 + p3);
            uint2 u; u.x = pack2bf(p0, p1); u.y = pack2bf(p2, p3);
            *(uint2*)&Pb0[(size_t)(it * 16 + li) * 136 + w * 16 + qd * 4] = u;
        }
    }
    __syncthreads();

    // ---- steady: interval t does PV(t-1) + S(t); one barrier ----
    #pragma unroll 1
    for (int t = 1; t < N_ / 128; ++t) {
        const ushort* Pr = ((t - 1) & 1) ? Pb1 : Pb0;
        ushort*       Pw = ((t - 1) & 1) ? Pb0 : Pb1;
        const size_t jprev = (size_t)(t - 1) * 128;

        // K(t): consumed at S(t), far away
        s8v nk0 = *(const s8v*)(kptr + (size_t)t * 128 * 64);
        s8v nk1 = *(const s8v*)(kptr + (size_t)t * 128 * 64 + 32);

        // PV(t-1), V loads rolled (2 frag-sets in flight)
        s8v vfA[4], vfB[4];
        #pragma unroll
        for (int ct = 0; ct < 4; ++ct) vfA[ct] = *(const s8v*)(vptr[ct] + jprev);
        #pragma unroll
        for (int ct = 0; ct < 4; ++ct) vfB[ct] = *(const s8v*)(vptr[ct] + jprev + 32);
        pv_chunk(Pr, li, qd, 0, vfA, acc);
        #pragma unroll
        for (int ct = 0; ct < 4; ++ct) vfA[ct] = *(const s8v*)(vptr[ct] + jprev + 64);
        pv_chunk(Pr, li, qd, 1, vfB, acc);
        #pragma unroll
        for (int ct = 0; ct < 4; ++ct) vfB[ct] = *(const s8v*)(vptr[ct] + jprev + 96);
        pv_chunk(Pr, li, qd, 2, vfA, acc);
        pv_chunk(Pr, li, qd, 3, vfB, acc);

        // S(t)
        f4v sac[2];
        #pragma unroll
        for (int it = 0; it < 2; ++it) {
            sac[it] = (f4v){0.f, 0.f, 0.f, 0.f};
            sac[it] = MF32(nk0, qf[it][0], sac[it]);
            sac[it] = MF32(nk1, qf[it][1], sac[it]);
        }
        #pragma unroll
        for (int it = 0; it < 2; ++it) {
            const float p0 = exp2f(sac[it][0]);
            const float p1 = exp2f(sac[it][1]);
            const float p2 = exp2f(sac[it][2]);
            const float p3 = exp2f(sac[it][3]);
            lp[it] += (p0 + p1) + (p2 + p3);
            uint2 u; u.x = pack2bf(p0, p1); u.y = pack2bf(p2, p3);
            *(uint2*)&Pw[(size_t)(it * 16 + li) * 136 + w * 16 + qd * 4] = u;
        }
        __syncthreads();
    }

    // ---- tail PV ----
    {
        const ushort* Pr = ((N_ / 128 - 1) & 1) ? Pb1 : Pb0;
        const size_t jprev = (size_t)(N_ / 128 - 1) * 128;
        s8v vfA[4], vfB[4];
        #pragma unroll
        for (int ct = 0; ct < 4; ++ct) vfA[ct] = *(const s8v*)(vptr[ct] + jprev);
        #pragma unroll
        for (int ct = 0; ct < 4; ++ct) vfB[ct] = *(const s8v*)(vptr[ct] + jprev + 32);
        pv_chunk(Pr, li, qd, 0, vfA, acc);
        #pragma unroll
        for (int ct = 0; ct < 4; ++ct) vfA[ct] = *(const s8v*)(vptr[ct] + jprev + 64);
        pv_chunk(Pr, li, qd, 1, vfB, acc);
        #pragma unroll
        for (int ct = 0; ct < 4; ++ct) vfB[ct] = *(const s8v*)(vptr[ct] + jprev + 96);
        pv_chunk(Pr, li, qd, 2, vfA, acc);
        pv_chunk(Pr, li, qd, 3, vfB, acc);
    }

    // ---- l: reduce over qd (shfl), waves (LDS), then 1/l per i ----
    #pragma unroll
    for (int it = 0; it < 2; ++it) {
        lp[it] += __shfl_xor(lp[it], 16, 64);
        lp[it] += __shfl_xor(lp[it], 32, 64);
    }
    if (qd == 0) {
        #pragma unroll
        for (int it = 0; it < 2; ++it) l_s[w * 32 + it * 16 + li] = lp[it];
    }
    __syncthreads();
    if (tid < 32) {
        float t = 0.f;
        #pragma unroll
        for (int ww = 0; ww < 8; ++ww) t += l_s[ww * 32 + tid];
        linv[tid] = 1.0f / t;
    }
    __syncthreads();

    // ---- epilogue: float4 rows (i-contiguous per lane thanks to PV swap) ----
    const float g = gamma[0];
    f4v invv[2];
    #pragma unroll
    for (int it = 0; it < 2; ++it)
        invv[it] = *(const f4v*)&linv[it * 16 + qd * 4];
    #pragma unroll
    for (int ct = 0; ct < 4; ++ct) {
        const int c = w * 64 + ct * 16 + li;
        #pragma unroll
        for (int it = 0; it < 2; ++it) {
            const size_t off = ((size_t)b * C_ + c) * N_ + i_base + it * 16 + qd * 4;
            float4 xr = *(const float4*)&x[off];
            float4 o;
            o.x = g * acc[ct][it][0] * invv[it][0] + xr.x;
            o.y = g * acc[ct][it][1] * invv[it][1] + xr.y;
            o.z = g * acc[ct][it][2] * invv[it][2] + xr.z;
            o.w = g * acc[ct][it][3] * invv[it][3] + xr.w;
            *(float4*)&out[off] = o;
        }
    }
}

// ---------------------------------------------------------------------------
extern "C" void kernel_launch(void* const* d_in, const int* in_sizes, int n_in,
                              void* d_out, int out_size, void* d_ws, size_t ws_size,
                              hipStream_t stream)
{
    const float* x     = (const float*)d_in[0];
    const float* Wq    = (const float*)d_in[1];
    const float* bq    = (const float*)d_in[2];
    const float* Wk    = (const float*)d_in[3];
    const float* bk    = (const float*)d_in[4];
    const float* Wv    = (const float*)d_in[5];
    const float* bv    = (const float*)d_in[6];
    const float* gamma = (const float*)d_in[7];
    float* out = (float*)d_out;

    // ws (ushort): vB [B][512][N] | qT [B][N][64] | kT [B][N][64] | Wb [640][512]
    ushort* vB = (ushort*)d_ws;
    ushort* qT = vB + (size_t)B_ * C_ * N_;
    ushort* kT = qT + (size_t)B_ * N_ * 64;
    ushort* Wb = kT + (size_t)B_ * N_ * 64;

    wconv_kernel<<<dim3(640), 256, 0, stream>>>(Wq, Wk, Wv, Wb);
    qkv_fused<<<dim3(N_ / 32, B_), 256, 0, stream>>>(x, Wb, bq, bk, bv, qT, kT, vB);
    attn_mfma<<<dim3(512), 512, 18560, stream>>>(qT, kT, vB, x, gamma, out);
}